// Round 12
// baseline (270.412 us; speedup 1.0000x reference)
//
#include <hip/hip_runtime.h>
#include <hip/hip_bf16.h>

#define EMBED 768
#define HEADS 12
#define WIN 64
#define DH 64
#define KDIM 768
#define NTILE 12      // KDIM / 64

typedef unsigned short u16;
typedef unsigned int u32;
typedef __attribute__((ext_vector_type(8))) short bf16x8;
typedef __attribute__((ext_vector_type(4))) float f32x4;

__device__ __forceinline__ u16 f2bf(float f) {
  union { float f; u32 u; } x; x.f = f;
  return (u16)((x.u + 0x7fffu + ((x.u >> 16) & 1u)) >> 16);
}

// ---------------- fp32 -> bf16 convert ----------------
__global__ void cvt_f32_bf16(const float* __restrict__ in, u16* __restrict__ out, int n4) {
  int i = blockIdx.x * blockDim.x + threadIdx.x;
  if (i >= n4) return;
  float4 v = ((const float4*)in)[i];
  ushort4 o;
  o.x = f2bf(v.x); o.y = f2bf(v.y); o.z = f2bf(v.z); o.w = f2bf(v.w);
  ((ushort4*)out)[i] = o;
}

// Per-head-interleaved QKV weights: out row r = h*192 + {Wq|Wk|Wv}[h*64+d]
__global__ void cvt_wqkv(const float* __restrict__ Wq, const float* __restrict__ Wk,
                         const float* __restrict__ Wv, const float* __restrict__ bq,
                         const float* __restrict__ bk, const float* __restrict__ bv,
                         u16* __restrict__ Wp, float* __restrict__ bp) {
  int i = blockIdx.x * 256 + threadIdx.x;        // one float4 each
  if (i >= 2304 * 192) return;
  int r = i / 192, c4 = i % 192;
  int h = r / 192, t = (r % 192) / 64, d = r % 64;
  const float* W = (t == 0) ? Wq : (t == 1) ? Wk : Wv;
  float4 v = *(const float4*)(W + (size_t)(h * 64 + d) * 768 + c4 * 4);
  ushort4 o;
  o.x = f2bf(v.x); o.y = f2bf(v.y); o.z = f2bf(v.z); o.w = f2bf(v.w);
  *(ushort4*)(Wp + (size_t)r * 768 + c4 * 4) = o;
  if (c4 == 0) {
    const float* bb = (t == 0) ? bq : (t == 1) ? bk : bv;
    bp[r] = bb[h * 64 + d];
  }
}

// ---------------- Fused QKV-projection + window attention ----------------
// Block = 128 rows (2 windows) x 192 cols, 768 thr = 12 waves (2M x 6N;
// per-wave 64x32, acc 32 regs). LDS 40KB single-buffered staging; attn reuses
// a one-window 27.6KB area with sequential window processing. Target:
// 2 blocks/CU = 24 waves = 6/SIMD (launch_bounds caps regs at 85).
__global__ __launch_bounds__(768, 6)
void qkva(const u16* __restrict__ A, const u16* __restrict__ Bw,
          const float* __restrict__ biasp, u16* __restrict__ O) {
  __shared__ char sc_[40960];                    // A 16K @0; B 24K @16384; attn 27.6K @0
  const int tid = threadIdx.x;
  const int lane = tid & 63;
  const int wid = tid >> 6;                      // 0..11
  const int wr = wid / 6, wc = wid % 6;          // 2M x 6N
  const int l15 = lane & 15;

  const int cpx = gridDim.x >> 3;
  int bid = blockIdx.x;
  bid = (bid & 7) * cpx + (bid >> 3);            // grid 3072 % 8 == 0
  const int head = bid % HEADS;
  const int brow = (bid / HEADS) << 7;
  const int bcolw = head * 192;

  const int srow = tid >> 3;                     // 0..95
  const int scol = ((tid & 7) ^ (srow & 7)) << 3;   // T2 pre-swizzled source
  const u16* Asrc = A + (size_t)(brow + srow) * KDIM + scol;
  const u16* Bsrc = Bw + (size_t)(bcolw + srow) * KDIM + scol;

  const int swz = (l15 & 7) << 4;
  const int cb0 = ((lane >> 4) << 4) ^ swz;
  const int cb1 = (((lane >> 4) + 4) << 4) ^ swz;
  auto pA = [&](int mi) -> const char* {
    return sc_ + ((wr << 6) + (mi << 4) + l15) * 128;
  };
  auto pB = [&](int nj) -> const char* {
    return sc_ + 16384 + ((wc << 5) + (nj << 4) + l15) * 128;
  };

  f32x4 acc[4][2];
#pragma unroll
  for (int m = 0; m < 4; ++m)
#pragma unroll
    for (int n = 0; n < 2; ++n) acc[m][n] = (f32x4){0.f, 0.f, 0.f, 0.f};

  for (int t = 0; t < NTILE; ++t) {
    const int kt = t << 6;
    // ---- stage tile t (single buffer): A rows 0-95, A rows 96-127, B rows 0-191 ----
    __builtin_amdgcn_global_load_lds(
        (const __attribute__((address_space(1))) void*)(Asrc + kt),
        (__attribute__((address_space(3))) void*)(sc_ + tid * 16), 16, 0, 0);
    if (tid < 256)                                // rows 96..127 (wave-uniform branch)
      __builtin_amdgcn_global_load_lds(
          (const __attribute__((address_space(1))) void*)(Asrc + (size_t)96 * KDIM + kt),
          (__attribute__((address_space(3))) void*)(sc_ + 12288 + tid * 16), 16, 0, 0);
#pragma unroll
    for (int u = 0; u < 2; ++u)
      __builtin_amdgcn_global_load_lds(
          (const __attribute__((address_space(1))) void*)(Bsrc + (size_t)(u * 96) * KDIM + kt),
          (__attribute__((address_space(3))) void*)(sc_ + 16384 + u * 12288 + tid * 16), 16, 0, 0);
    __syncthreads();                              // stage landed
    bf16x8 rb[2][2];
#pragma unroll
    for (int nj = 0; nj < 2; ++nj) {
      rb[nj][0] = *(const bf16x8*)(pB(nj) + cb0);
      rb[nj][1] = *(const bf16x8*)(pB(nj) + cb1);
    }
#pragma unroll
    for (int mi = 0; mi < 4; ++mi) {
      bf16x8 ra0 = *(const bf16x8*)(pA(mi) + cb0);
      bf16x8 ra1 = *(const bf16x8*)(pA(mi) + cb1);
#pragma unroll
      for (int nj = 0; nj < 2; ++nj) {
        acc[mi][nj] = __builtin_amdgcn_mfma_f32_16x16x32_bf16(ra0, rb[nj][0], acc[mi][nj], 0, 0, 0);
        acc[mi][nj] = __builtin_amdgcn_mfma_f32_16x16x32_bf16(ra1, rb[nj][1], acc[mi][nj], 0, 0, 0);
      }
    }
    __syncthreads();                              // reads done before next stage
  }

  // ---- attention: one-window LDS area, windows sequential (win == wr group) ----
  u16* qp = (u16*)sc_;                            // [64][72]  Q, later P
  u16* kp = qp + 4608;                            // [64][72]  K
  u16* vp = kp + 4608;                            // [64][72]  V^T (d-major)
  const int g8 = (lane >> 4) << 3;
  const int g4 = (lane >> 4) << 2;

  for (int win = 0; win < 2; ++win) {
    if (wr == win) {
      // scatter this wave's acc (rows = window's 64 rows, cols wc*32..+32)
#pragma unroll
      for (int mi = 0; mi < 4; ++mi) {
        const int row0 = (mi << 4) + g4;
#pragma unroll
        for (int nj = 0; nj < 2; ++nj) {
          const int col = (wc << 5) + (nj << 4) + l15;
          const float bb = biasp[bcolw + col];
#pragma unroll
          for (int rr = 0; rr < 4; ++rr) {
            const int rloc = row0 + rr;
            const u16 val = f2bf(acc[mi][nj][rr] + bb);
            if (col < 64)       qp[rloc * 72 + col] = val;
            else if (col < 128) kp[rloc * 72 + (col - 64)] = val;
            else                vp[(col - 128) * 72 + rloc] = val;
          }
        }
      }
    }
    __syncthreads();
    if (wr == win && wc < 4) {
      const int qt = wc;                          // 4 waves, 16 rows each
      const int rown = qt * 16 + l15;
      f32x4 sacc[4];
#pragma unroll
      for (int t = 0; t < 4; ++t) sacc[t] = (f32x4){0.f, 0.f, 0.f, 0.f};
      bf16x8 aq0 = *(const bf16x8*)(qp + rown * 72 + g8);
      bf16x8 aq1 = *(const bf16x8*)(qp + rown * 72 + 32 + g8);
#pragma unroll
      for (int t = 0; t < 4; ++t) {
        const int kr = t * 16 + l15;
        bf16x8 bk0 = *(const bf16x8*)(kp + kr * 72 + g8);
        bf16x8 bk1 = *(const bf16x8*)(kp + kr * 72 + 32 + g8);
        sacc[t] = __builtin_amdgcn_mfma_f32_16x16x32_bf16(aq0, bk0, sacc[t], 0, 0, 0);
        sacc[t] = __builtin_amdgcn_mfma_f32_16x16x32_bf16(aq1, bk1, sacc[t], 0, 0, 0);
      }
#pragma unroll
      for (int t = 0; t < 4; ++t)
#pragma unroll
        for (int r = 0; r < 4; ++r) sacc[t][r] *= 0.125f;
#pragma unroll
      for (int r = 0; r < 4; ++r) {
        float m0 = fmaxf(fmaxf(sacc[0][r], sacc[1][r]), fmaxf(sacc[2][r], sacc[3][r]));
#pragma unroll
        for (int msk = 1; msk < 16; msk <<= 1) m0 = fmaxf(m0, __shfl_xor(m0, msk));
        float s0 = 0.f;
#pragma unroll
        for (int t = 0; t < 4; ++t) {
          float e = __expf(sacc[t][r] - m0);
          sacc[t][r] = e;
          s0 += e;
        }
#pragma unroll
        for (int msk = 1; msk < 16; msk <<= 1) s0 += __shfl_xor(s0, msk);
        const float inv = 1.f / s0;
#pragma unroll
        for (int t = 0; t < 4; ++t) sacc[t][r] *= inv;
      }
      // P -> qp (wave's own 16 rows only; same-wave write->read ordering)
#pragma unroll
      for (int t = 0; t < 4; ++t)
#pragma unroll
        for (int r = 0; r < 4; ++r)
          qp[(qt * 16 + g4 + r) * 72 + t * 16 + l15] = f2bf(sacc[t][r]);
      // PV
      f32x4 oacc[4];
#pragma unroll
      for (int t = 0; t < 4; ++t) oacc[t] = (f32x4){0.f, 0.f, 0.f, 0.f};
      bf16x8 ap0 = *(const bf16x8*)(qp + rown * 72 + g8);
      bf16x8 ap1 = *(const bf16x8*)(qp + rown * 72 + 32 + g8);
#pragma unroll
      for (int t = 0; t < 4; ++t) {
        const int dr = t * 16 + l15;
        bf16x8 bv0 = *(const bf16x8*)(vp + dr * 72 + g8);
        bf16x8 bv1 = *(const bf16x8*)(vp + dr * 72 + 32 + g8);
        oacc[t] = __builtin_amdgcn_mfma_f32_16x16x32_bf16(ap0, bv0, oacc[t], 0, 0, 0);
        oacc[t] = __builtin_amdgcn_mfma_f32_16x16x32_bf16(ap1, bv1, oacc[t], 0, 0, 0);
      }
      // O direct to global: 4 rows x 32B contiguous per store op -> no amplification
#pragma unroll
      for (int t = 0; t < 4; ++t)
#pragma unroll
        for (int r = 0; r < 4; ++r)
          O[(size_t)(brow + win * 64 + qt * 16 + g4 + r) * 768 + head * 64 + t * 16 + l15] =
              f2bf(oacc[t][r]);
    }
    __syncthreads();                              // area free for next window
  }
}

// ---------------- 128x128 NT GEMM (Wo), m97-style single-buffer, 3 blocks/CU ----------------
__global__ __launch_bounds__(256, 3)
void gemm128(const u16* __restrict__ A, const u16* __restrict__ Bw,
             const float* __restrict__ bias, float* __restrict__ dF, int N) {
  __shared__ char sc_[32768];                    // A 16K @0; B 16K @16384 (single buf)
  const int tid = threadIdx.x;
  const int lane = tid & 63;
  const int wid = tid >> 6;
  const int wr = wid >> 1, wc = wid & 1;
  const int l15 = lane & 15;

  const int nbx = N >> 7;
  const int cpx = gridDim.x >> 3;
  int bid = blockIdx.x;
  bid = (bid & 7) * cpx + (bid >> 3);            // grid 1536 % 8 == 0
  const int brow = (bid / nbx) << 7;
  const int bcol = (bid % nbx) << 7;

  const int srow = tid >> 3;
  const int scol = ((tid & 7) ^ (srow & 7)) << 3;
  const u16* Asrc = A + (size_t)(brow + srow) * KDIM + scol;
  const u16* Bsrc = Bw + (size_t)(bcol + srow) * KDIM + scol;
  const int lds_woff = wid << 10;

  auto STAGE_A = [&](int u, int kt) {
    __builtin_amdgcn_global_load_lds(
        (const __attribute__((address_space(1))) void*)(Asrc + (size_t)(u << 5) * KDIM + kt),
        (__attribute__((address_space(3))) void*)(sc_ + (u << 12) + lds_woff), 16, 0, 0);
  };
  auto STAGE_B = [&](int u, int kt) {
    __builtin_amdgcn_global_load_lds(
        (const __attribute__((address_space(1))) void*)(Bsrc + (size_t)(u << 5) * KDIM + kt),
        (__attribute__((address_space(3))) void*)(sc_ + 16384 + (u << 12) + lds_woff), 16, 0, 0);
  };

  const int swz = (l15 & 7) << 4;
  const int cb0 = ((lane >> 4) << 4) ^ swz;
  const int cb1 = (((lane >> 4) + 4) << 4) ^ swz;
  auto pA = [&](int mi) -> const char* {
    return sc_ + (((wr << 6) + (mi << 4) + l15)) * 128;
  };
  auto pB = [&](int nj) -> const char* {
    return sc_ + 16384 + (((wc << 6) + (nj << 4) + l15)) * 128;
  };

  f32x4 acc[4][4];
#pragma unroll
  for (int m = 0; m < 4; ++m)
#pragma unroll
    for (int n = 0; n < 4; ++n) acc[m][n] = (f32x4){0.f, 0.f, 0.f, 0.f};

  for (int t = 0; t < NTILE; ++t) {
    const int kt = t << 6;
#pragma unroll
    for (int u = 0; u < 4; ++u) STAGE_A(u, kt);
#pragma unroll
    for (int u = 0; u < 4; ++u) STAGE_B(u, kt);
    __syncthreads();                             // stage landed
    bf16x8 rb[4][2];
#pragma unroll
    for (int nj = 0; nj < 4; ++nj) {
      rb[nj][0] = *(const bf16x8*)(pB(nj) + cb0);
      rb[nj][1] = *(const bf16x8*)(pB(nj) + cb1);
    }
#pragma unroll
    for (int q = 0; q < 4; ++q) {
      bf16x8 ra0 = *(const bf16x8*)(pA(q) + cb0);
      bf16x8 ra1 = *(const bf16x8*)(pA(q) + cb1);
#pragma unroll
      for (int nj = 0; nj < 4; ++nj) {
        acc[q][nj] = __builtin_amdgcn_mfma_f32_16x16x32_bf16(ra0, rb[nj][0], acc[q][nj], 0, 0, 0);
        acc[q][nj] = __builtin_amdgcn_mfma_f32_16x16x32_bf16(ra1, rb[nj][1], acc[q][nj], 0, 0, 0);
      }
    }
    __syncthreads();                             // all reads done before re-stage
  }

  // f32 epilogue: two col-half passes via 32KB LDS (128x64 f32)
  float* smf = (float*)sc_;
#pragma unroll
  for (int p = 0; p < 2; ++p) {
    if (p) __syncthreads();
    if (wc == p) {
#pragma unroll
      for (int mi = 0; mi < 4; ++mi)
#pragma unroll
        for (int nj = 0; nj < 4; ++nj) {
          const int col = (nj << 4) + l15;
          const float bb = bias[bcol + (p << 6) + col];
          const int row0 = (wr << 6) + (mi << 4) + ((lane >> 4) << 2);
#pragma unroll
          for (int rr = 0; rr < 4; ++rr)
            smf[(row0 + rr) << 6 | col] = acc[mi][nj][rr] + bb;
        }
    }
    __syncthreads();
#pragma unroll
    for (int it = 0; it < 8; ++it) {
      const int f = (it << 8) + tid;
      const int row = f >> 4, c4 = f & 15;
      float4 v = *(const float4*)(smf + (row << 6) + (c4 << 2));
      *(float4*)(dF + (size_t)(brow + row) * N + bcol + (p << 6) + (c4 << 2)) = v;
    }
  }
}

extern "C" void kernel_launch(void* const* d_in, const int* in_sizes, int n_in,
                              void* d_out, int out_size, void* d_ws, size_t ws_size,
                              hipStream_t stream) {
  const float* q  = (const float*)d_in[0];
  const float* Wq = (const float*)d_in[3];
  const float* bq = (const float*)d_in[4];
  const float* Wk = (const float*)d_in[5];
  const float* bk = (const float*)d_in[6];
  const float* Wv = (const float*)d_in[7];
  const float* bv = (const float*)d_in[8];
  const float* Wo = (const float*)d_in[9];
  const float* bo = (const float*)d_in[10];

  const int C = EMBED;
  const int M = in_sizes[0] / C;                 // 32768
  const size_t xsz = (size_t)M * C;
  const size_t wsz = (size_t)C * C;

  u16* Xb = (u16*)d_out;                         // scratch (overwritten by Wo GEMM)
  u16* Ob = (u16*)d_ws;                          // attention output, bf16 [M][768]
  u16* Wp = Ob + xsz;                            // per-head QKV weights [2304][768]
  u16* Wob = Wp + 3 * wsz;
  float* biasp = (float*)(Wob + wsz);            // 2304 f32 permuted bias

  {
    int n4 = (int)(xsz >> 2);
    cvt_f32_bf16<<<(n4 + 255) / 256, 256, 0, stream>>>(q, Xb, n4);
    int w4 = (int)(wsz >> 2);
    cvt_f32_bf16<<<(w4 + 255) / 256, 256, 0, stream>>>(Wo, Wob, w4);
    cvt_wqkv<<<(2304 * 192 + 255) / 256, 256, 0, stream>>>(Wq, Wk, Wv, bq, bk, bv, Wp, biasp);
  }

  // Fused QKV projection + attention: 256 rowblocks x 12 heads = 3072 blocks (768 thr)
  qkva<<<(M / 128) * HEADS, 768, 0, stream>>>(Xb, Wp, biasp, Ob);

  // Output projection: 1536 blocks (2 rounds @ 3/CU)
  gemm128<<<(M / 128) * (C / 128), 256, 0, stream>>>(Ob, Wob, bo, (float*)d_out, C);
}